// Round 8
// baseline (118.630 us; speedup 1.0000x reference)
//
#include <hip/hip_runtime.h>

// PointSIFT: octant-wise nearest neighbor within radius + group.
// B=2, N=4096, C=64 fixed; xyz uniform in [0,1)^3, radius=0.25.
//
// Spatial-pruning design (selection is order-independent: winner =
// lexicographic min of packed u64 (key<<32|idx), which reproduces the
// reference's first-min + index tie-break exactly, so we may scan any
// superset of the valid candidates in any order):
//   1. build_grid: counting-sort points into a 4x4x4 cell grid (cell width
//      0.25 = radius). Sorted float4 = (x,y,z, orig_idx bits) in d_ws.
//   2. select: block = 8 consecutive SORTED queries (spatially tight).
//      Candidate box = cells overlapping [qmin-r, qmax+r] per axis (superset
//      of all |d|<r candidates). Per-thread LDS scoreboard indexed by octant
//      code, updated with fire-and-forget ds_min_u64. Writes out2 directly.
//   3. gather: one thread per output element (unchanged).
//
// Packed key: hi = float_bits(dist) - (float_bits(1e-10f)+1)
//   - dist <= 1e-10 (incl. self) wraps to huge            -> loses
//   - dist >= judge forced to 0xFFFFFFFF (strict-< exact) -> loses
//   - valid dists monotone; ties on key fall to min idx = ref tie-break
#define BB 2
#define NN 4096
#define CC 64
#define QPB 8               // queries per select block (sorted order)
#define TPQ 32              // threads per query
#define NT 256              // threads per block

// flat output layout (all float32):
//   out0 grouped_xyz   [B,N,8,3]
//   out1 grouped_points[B,N,8,67]
//   out2 idx (as float)[B,N,8]
#define OUT0_OFF 0
#define OUT1_OFF (BB * NN * 8 * 3)               /* 196608 */
#define OUT2_OFF (OUT1_OFF + BB * NN * 8 * 67)   /* 4587520 */

// d_ws layout: sorted float4 [B*NN], then offsets int [B*65]
#define WS_SORTED_BYTES (BB * NN * 16)

__global__ __launch_bounds__(256) void build_grid(
    const float* __restrict__ xyz, float4* __restrict__ sorted,
    int* __restrict__ offsets)
{
    __shared__ int hist[64];
    __shared__ int offs[65];
    const int b = blockIdx.x;
    const int tid = threadIdx.x;
    if (tid < 64) hist[tid] = 0;
    __syncthreads();
    const float* src = xyz + (size_t)b * NN * 3;
    for (int p = tid; p < NN; p += 256) {
        float x = src[p * 3 + 0], y = src[p * 3 + 1], z = src[p * 3 + 2];
        int cell = (((int)(x * 4.0f)) << 4) | (((int)(y * 4.0f)) << 2)
                 | ((int)(z * 4.0f));            // x in [0,1) -> cell in [0,64)
        atomicAdd(&hist[cell], 1);
    }
    __syncthreads();
    if (tid == 0) {                              // tiny exclusive scan
        int acc = 0;
        for (int c = 0; c < 64; ++c) { offs[c] = acc; acc += hist[c]; }
        offs[64] = acc;
    }
    __syncthreads();
    if (tid < 65) offsets[b * 65 + tid] = offs[tid];
    if (tid < 64) hist[tid] = offs[tid];         // reuse as scatter cursors
    __syncthreads();
    float4* dst = sorted + (size_t)b * NN;
    for (int p = tid; p < NN; p += 256) {
        float x = src[p * 3 + 0], y = src[p * 3 + 1], z = src[p * 3 + 2];
        int cell = (((int)(x * 4.0f)) << 4) | (((int)(y * 4.0f)) << 2)
                 | ((int)(z * 4.0f));
        int pos = atomicAdd(&hist[cell], 1);     // order within cell arbitrary
        dst[pos] = make_float4(x, y, z, __uint_as_float((unsigned)p));
    }
}

__global__ __launch_bounds__(NT, 4) void pointsift_select(
    const float4* __restrict__ sorted, const int* __restrict__ offsets,
    const float* __restrict__ radius_p, float* __restrict__ out)
{
    __shared__ unsigned long long s_sb[8 * NT];  // 16 KiB (key<<32|idx)
    __shared__ int s_off[65];

    const int tid = threadIdx.x;
    const int blk = blockIdx.x;
    const int b = blk >> 9;                      // 512 blocks per batch
    const int qslot = (blk & 511) * QPB;         // sorted-array slot base
    const float4* sb = sorted + (size_t)b * NN;

    if (tid < 65) s_off[tid] = offsets[b * 65 + tid];

    const float r = radius_p[0];
    const float judge = __fmul_rn(r, r);
    const unsigned OFFC = __float_as_uint(1e-10f) + 1u;
    const unsigned seedkey = __float_as_uint(judge) - OFFC;

    // own query (from sorted array; coords are bit-identical copies)
    const float4 q = sb[qslot + (tid >> 5)];
    const unsigned n = __float_as_uint(q.w);     // original index
    const float qx = q.x, qy = q.y, qz = q.z;
    const int sub = tid & (TPQ - 1);

    // seed own 8 columns (only thread tid ever touches column tid)
    const unsigned long long seed64 = ((unsigned long long)seedkey << 32) | n;
    unsigned long long* mycol = s_sb + tid;
    #pragma unroll
    for (int o = 0; o < 8; ++o) mycol[o * NT] = seed64;

    // block candidate box: cells overlapping [min-r, max+r] over the block's
    // 8 queries (uniform across threads -> no divergence)
    float mnx = 1e9f, mxx = -1e9f, mny = 1e9f, mxy = -1e9f, mnz = 1e9f, mxz = -1e9f;
    #pragma unroll
    for (int k = 0; k < QPB; ++k) {
        float4 qq = sb[qslot + k];
        mnx = fminf(mnx, qq.x); mxx = fmaxf(mxx, qq.x);
        mny = fminf(mny, qq.y); mxy = fmaxf(mxy, qq.y);
        mnz = fminf(mnz, qq.z); mxz = fmaxf(mxz, qq.z);
    }
    const int lx = max(0, (int)((mnx - r) * 4.0f));
    const int hx = min(3, (int)((mxx + r) * 4.0f));
    const int ly = max(0, (int)((mny - r) * 4.0f));
    const int hy = min(3, (int)((mxy + r) * 4.0f));
    const int lz = max(0, (int)((mnz - r) * 4.0f));
    const int hz = min(3, (int)((mxz + r) * 4.0f));

    __syncthreads();                             // s_off ready

    for (int cx = lx; cx <= hx; ++cx) {
        for (int cy = ly; cy <= hy; ++cy) {
            const int cb = (cx << 4) | (cy << 2);
            const int s = s_off[cb + lz];
            const int e = s_off[cb + hz + 1];    // cz-contiguous run
            #pragma unroll 2
            for (int p = s + sub; p < e; p += TPQ) {
                float4 c = sb[p];
                // diff = candidate - query, fp32, no contraction (match ref)
                float dx = __fsub_rn(c.x, qx);
                float dy = __fsub_rn(c.y, qy);
                float dz = __fsub_rn(c.z, qz);
                float dist = __fadd_rn(__fadd_rn(__fmul_rn(dx, dx),
                                                 __fmul_rn(dy, dy)),
                                       __fmul_rn(dz, dz));
                unsigned ikey = __float_as_uint(dist) - OFFC;
                ikey = (dist >= judge) ? 0xFFFFFFFFu : ikey;
                // octant code = trunc(d+1.0f) dot [4,2,1]; &7 folds the d~1.0
                // boundary (dist >> judge there, so it loses anyway)
                int code = ((((int)__fadd_rn(dx, 1.0f)) * 4 +
                             ((int)__fadd_rn(dy, 1.0f)) * 2 +
                             ((int)__fadd_rn(dz, 1.0f))) & 7);
                // fire-and-forget ds_min_u64 on own column
                atomicMin(&s_sb[code * NT + tid],
                          ((unsigned long long)ikey << 32) |
                          (unsigned long long)__float_as_uint(c.w));
            }
        }
    }

    // read back own columns (private; DS pipe in-order per wave)
    unsigned long long bv[8];
    #pragma unroll
    for (int o = 0; o < 8; ++o) bv[o] = mycol[o * NT];

    // butterfly reduce over the 32 stripe-threads of this query (lanes are
    // 32-aligned within the wave); packed u64 min = first-min + idx tie-break
    #pragma unroll
    for (int mm = 1; mm < TPQ; mm <<= 1) {
        #pragma unroll
        for (int o = 0; o < 8; ++o) {
            unsigned long long ov = __shfl_xor(bv[o], mm, 64);
            if (ov < bv[o]) bv[o] = ov;
        }
    }

    // stripe-leader writes final indices for its query
    if (sub == 0) {
        const size_t tb = ((size_t)b * NN + n) * 8;
        #pragma unroll
        for (int o = 0; o < 8; ++o)
            out[OUT2_OFF + tb + o] = (float)(unsigned)(bv[o] & 0xFFFFFFFFu);
    }
}

// one thread per output element: item = tuple*70 + j
//   j in [0,67): out1[t*67+j]  (j<3: grouped_xyz channel, else feature j-3)
//   j in [67,70): out0[t*3 + (j-67)]
__global__ __launch_bounds__(256) void pointsift_gather(
    const float* __restrict__ xyz, const float* __restrict__ points,
    float* __restrict__ out)
{
    const unsigned item = blockIdx.x * 256u + threadIdx.x;   // grid is exact
    const unsigned t = item / 70u;
    const unsigned j = item - t * 70u;
    const unsigned bn = t >> 3;               // b*N + n
    const unsigned b = bn >> 12;
    const unsigned n = bn & (NN - 1);
    const int i = (int)out[OUT2_OFF + t];     // selected idx (broadcast read)
    const float* xb = xyz + (size_t)b * NN * 3;
    if (j < 67u) {
        float v;
        if (j < 3u) v = __fsub_rn(xb[i * 3 + j], xb[n * 3 + j]);
        else        v = points[((size_t)b * NN + i) * CC + (j - 3u)];
        out[OUT1_OFF + (size_t)t * 67 + j] = v;
    } else {
        const unsigned c = j - 67u;
        out[OUT0_OFF + (size_t)t * 3 + c] =
            __fsub_rn(xb[i * 3 + c], xb[n * 3 + c]);
    }
}

extern "C" void kernel_launch(void* const* d_in, const int* in_sizes, int n_in,
                              void* d_out, int out_size, void* d_ws, size_t ws_size,
                              hipStream_t stream) {
    const float* xyz    = (const float*)d_in[0];
    const float* points = (const float*)d_in[1];
    const float* radius = (const float*)d_in[2];
    float* out = (float*)d_out;
    float4* ws_sorted = (float4*)d_ws;
    int* ws_offsets = (int*)((char*)d_ws + WS_SORTED_BYTES);

    // 1: counting-sort into 4x4x4 cells (one block per batch)
    hipLaunchKernelGGL(build_grid, dim3(BB), dim3(256), 0, stream,
                       xyz, ws_sorted, ws_offsets);
    // 2: pruned octant select -> out2 (1024 blocks)
    hipLaunchKernelGGL(pointsift_select,
                       dim3(BB * (NN / QPB)), dim3(NT), 0, stream,
                       ws_sorted, ws_offsets, radius, out);
    // 3: gather, one thread per element (16384*70/256 = 4480 blocks, exact)
    hipLaunchKernelGGL(pointsift_gather,
                       dim3(BB * NN * 8 * 70 / 256), dim3(256), 0, stream,
                       xyz, points, out);
}

// Round 9
// 112.662 us; speedup vs baseline: 1.0530x; 1.0530x over previous
//
#include <hip/hip_runtime.h>

// PointSIFT: octant-wise nearest neighbor within radius + group.
// B=2, N=4096, C=64 fixed; xyz uniform in [0,1)^3, radius=0.25.
//
// Two-kernel design:
//   1. build_grid: counting-sort points into a 4x4x4 cell grid (cell width
//      0.25 = radius). Sorted float4 = (x,y,z, orig_idx bits) in d_ws.
//      Wave-parallel prefix scan, 1024 threads.
//   2. select_gather: block = 8 consecutive SORTED queries (spatially tight).
//      Candidate box = cells overlapping [qmin-r, qmax+r] per axis (superset
//      of all |d|<r candidates; selection is order-independent because the
//      winner is the lexicographic min of packed u64 (key<<32|idx), which
//      reproduces the reference's first-min + index tie-break exactly).
//      Per-thread LDS scoreboard indexed by octant code, updated with
//      fire-and-forget ds_min_u64. Gather fused in the epilogue.
//
// Packed key: hi = float_bits(dist) - (float_bits(1e-10f)+1)
//   - dist <= 1e-10 (incl. self) wraps to huge            -> loses
//   - dist >= judge forced to 0xFFFFFFFF (strict-< exact) -> loses
//   - valid dists monotone; ties on key fall to min idx = ref tie-break
#define BB 2
#define NN 4096
#define CC 64
#define QPB 8               // queries per select block (sorted order)
#define TPQ 32              // threads per query
#define NT 256              // threads per select block

// flat output layout (all float32):
//   out0 grouped_xyz   [B,N,8,3]
//   out1 grouped_points[B,N,8,67]
//   out2 idx (as float)[B,N,8]
#define OUT0_OFF 0
#define OUT1_OFF (BB * NN * 8 * 3)               /* 196608 */
#define OUT2_OFF (OUT1_OFF + BB * NN * 8 * 67)   /* 4587520 */

// d_ws layout: sorted float4 [B*NN], then offsets int [B*65]
#define WS_SORTED_BYTES (BB * NN * 16)

__global__ __launch_bounds__(1024) void build_grid(
    const float* __restrict__ xyz, float4* __restrict__ sorted,
    int* __restrict__ offsets)
{
    __shared__ int hist[64];
    __shared__ int offs[65];
    const int b = blockIdx.x;
    const int tid = threadIdx.x;
    if (tid < 64) hist[tid] = 0;
    __syncthreads();
    const float* src = xyz + (size_t)b * NN * 3;
    #pragma unroll
    for (int p = tid; p < NN; p += 1024) {
        float x = src[p * 3 + 0], y = src[p * 3 + 1], z = src[p * 3 + 2];
        int cell = (((int)(x * 4.0f)) << 4) | (((int)(y * 4.0f)) << 2)
                 | ((int)(z * 4.0f));            // x in [0,1) -> cell in [0,64)
        atomicAdd(&hist[cell], 1);
    }
    __syncthreads();
    if (tid < 64) {                              // wave 0: shfl prefix scan
        int inc = hist[tid];
        #pragma unroll
        for (int d = 1; d < 64; d <<= 1) {
            int u = __shfl_up(inc, d, 64);
            if (tid >= d) inc += u;
        }
        offs[tid + 1] = inc;                     // inclusive -> offs[1..64]
        if (tid == 0) offs[0] = 0;
    }
    __syncthreads();
    if (tid < 65) offsets[b * 65 + tid] = offs[tid];
    if (tid < 64) hist[tid] = offs[tid];         // reuse as scatter cursors
    __syncthreads();
    float4* dst = sorted + (size_t)b * NN;
    #pragma unroll
    for (int p = tid; p < NN; p += 1024) {
        float x = src[p * 3 + 0], y = src[p * 3 + 1], z = src[p * 3 + 2];
        int cell = (((int)(x * 4.0f)) << 4) | (((int)(y * 4.0f)) << 2)
                 | ((int)(z * 4.0f));
        int pos = atomicAdd(&hist[cell], 1);     // order within cell arbitrary
        dst[pos] = make_float4(x, y, z, __uint_as_float((unsigned)p));
    }
}

__global__ __launch_bounds__(NT, 4) void select_gather(
    const float4* __restrict__ sorted, const int* __restrict__ offsets,
    const float* __restrict__ xyz, const float* __restrict__ points,
    const float* __restrict__ radius_p, float* __restrict__ out)
{
    __shared__ unsigned long long s_sb[8 * NT];  // 16 KiB (key<<32|idx)
    __shared__ int s_off[65];
    __shared__ int s_res[QPB * 8];               // winners per (query,octant)

    const int tid = threadIdx.x;
    const int blk = blockIdx.x;
    const int b = blk >> 9;                      // 512 blocks per batch
    const int qslot = (blk & 511) * QPB;         // sorted-array slot base
    const float4* sb = sorted + (size_t)b * NN;

    if (tid < 65) s_off[tid] = offsets[b * 65 + tid];

    const float r = radius_p[0];
    const float judge = __fmul_rn(r, r);
    const unsigned OFFC = __float_as_uint(1e-10f) + 1u;
    const unsigned seedkey = __float_as_uint(judge) - OFFC;

    // own query (from sorted array; coords are bit-identical copies)
    const int g = tid >> 5;                      // query group 0..7
    const float4 q = sb[qslot + g];
    const unsigned n = __float_as_uint(q.w);     // original index
    const float qx = q.x, qy = q.y, qz = q.z;
    const int sub = tid & (TPQ - 1);

    // seed own 8 columns (only thread tid ever touches column tid)
    const unsigned long long seed64 = ((unsigned long long)seedkey << 32) | n;
    unsigned long long* mycol = s_sb + tid;
    #pragma unroll
    for (int o = 0; o < 8; ++o) mycol[o * NT] = seed64;

    // block candidate box: cells overlapping [min-r, max+r] over the block's
    // 8 queries (uniform across threads -> no divergence)
    float mnx = 1e9f, mxx = -1e9f, mny = 1e9f, mxy = -1e9f, mnz = 1e9f, mxz = -1e9f;
    #pragma unroll
    for (int k = 0; k < QPB; ++k) {
        float4 qq = sb[qslot + k];
        mnx = fminf(mnx, qq.x); mxx = fmaxf(mxx, qq.x);
        mny = fminf(mny, qq.y); mxy = fmaxf(mxy, qq.y);
        mnz = fminf(mnz, qq.z); mxz = fmaxf(mxz, qq.z);
    }
    const int lx = max(0, (int)((mnx - r) * 4.0f));
    const int hx = min(3, (int)((mxx + r) * 4.0f));
    const int ly = max(0, (int)((mny - r) * 4.0f));
    const int hy = min(3, (int)((mxy + r) * 4.0f));
    const int lz = max(0, (int)((mnz - r) * 4.0f));
    const int hz = min(3, (int)((mxz + r) * 4.0f));

    __syncthreads();                             // s_off ready

    for (int cx = lx; cx <= hx; ++cx) {
        for (int cy = ly; cy <= hy; ++cy) {
            const int cb = (cx << 4) | (cy << 2);
            const int s = s_off[cb + lz];
            const int e = s_off[cb + hz + 1];    // cz-contiguous run
            #pragma unroll 4
            for (int p = s + sub; p < e; p += TPQ) {
                float4 c = sb[p];
                // diff = candidate - query, fp32, no contraction (match ref)
                float dx = __fsub_rn(c.x, qx);
                float dy = __fsub_rn(c.y, qy);
                float dz = __fsub_rn(c.z, qz);
                float dist = __fadd_rn(__fadd_rn(__fmul_rn(dx, dx),
                                                 __fmul_rn(dy, dy)),
                                       __fmul_rn(dz, dz));
                unsigned ikey = __float_as_uint(dist) - OFFC;
                ikey = (dist >= judge) ? 0xFFFFFFFFu : ikey;
                // octant code = trunc(d+1.0f) dot [4,2,1]; coords in [0,1)
                // -> d+1.0f in (0,2) -> each bit already 0/1
                int code = (((int)__fadd_rn(dx, 1.0f)) * 4 +
                            ((int)__fadd_rn(dy, 1.0f)) * 2 +
                            ((int)__fadd_rn(dz, 1.0f)));
                // fire-and-forget ds_min_u64 on own column
                atomicMin(&s_sb[code * NT + tid],
                          ((unsigned long long)ikey << 32) |
                          (unsigned long long)__float_as_uint(c.w));
            }
        }
    }

    // read back own columns (private; DS pipe in-order per wave)
    unsigned long long bv[8];
    #pragma unroll
    for (int o = 0; o < 8; ++o) bv[o] = mycol[o * NT];

    // butterfly reduce over the 32 stripe-threads of this query (lanes are
    // 32-aligned within the wave); packed u64 min = first-min + idx tie-break
    #pragma unroll
    for (int mm = 1; mm < TPQ; mm <<= 1) {
        #pragma unroll
        for (int o = 0; o < 8; ++o) {
            unsigned long long ov = __shfl_xor(bv[o], mm, 64);
            if (ov < bv[o]) bv[o] = ov;
        }
    }

    // stripe-leader publishes winners + writes out2
    if (sub == 0) {
        const size_t tb = ((size_t)b * NN + n) * 8;
        #pragma unroll
        for (int o = 0; o < 8; ++o) {
            int w = (int)(unsigned)(bv[o] & 0xFFFFFFFFu);
            s_res[g * 8 + o] = w;
            out[OUT2_OFF + tb + o] = (float)w;
        }
    }
    __syncthreads();

    // fused gather: each query-group (32 lanes) writes its own 8 tuples.
    // out1 row = 67 floats: c<3 -> grouped_xyz, else points[b,i,c-3].
    const float* xb = xyz + (size_t)b * NN * 3;
    const float* pb = points + (size_t)b * NN * CC;
    #pragma unroll
    for (int o = 0; o < 8; ++o) {
        const int i = s_res[g * 8 + o];
        const size_t t = ((size_t)b * NN + n) * 8 + o;
        // c = sub (0..31): 3 xyz + feats 0..28
        {
            const int c = sub;
            float v;
            if (c < 3) {
                v = __fsub_rn(xb[i * 3 + c], xb[n * 3 + c]);
                out[OUT0_OFF + t * 3 + c] = v;
            } else {
                v = pb[(size_t)i * CC + (c - 3)];
            }
            out[OUT1_OFF + t * 67 + c] = v;
        }
        // c = sub+32 (32..63): feats 29..60
        {
            const int c = sub + 32;
            out[OUT1_OFF + t * 67 + c] = pb[(size_t)i * CC + (c - 3)];
        }
        // c = sub+64 (64..66): feats 61..63
        if (sub < 3) {
            const int c = sub + 64;
            out[OUT1_OFF + t * 67 + c] = pb[(size_t)i * CC + (c - 3)];
        }
    }
}

extern "C" void kernel_launch(void* const* d_in, const int* in_sizes, int n_in,
                              void* d_out, int out_size, void* d_ws, size_t ws_size,
                              hipStream_t stream) {
    const float* xyz    = (const float*)d_in[0];
    const float* points = (const float*)d_in[1];
    const float* radius = (const float*)d_in[2];
    float* out = (float*)d_out;
    float4* ws_sorted = (float4*)d_ws;
    int* ws_offsets = (int*)((char*)d_ws + WS_SORTED_BYTES);

    // 1: counting-sort into 4x4x4 cells (one block per batch)
    hipLaunchKernelGGL(build_grid, dim3(BB), dim3(1024), 0, stream,
                       xyz, ws_sorted, ws_offsets);
    // 2: pruned octant select + fused gather (1024 blocks)
    hipLaunchKernelGGL(select_gather,
                       dim3(BB * (NN / QPB)), dim3(NT), 0, stream,
                       ws_sorted, ws_offsets, xyz, points, radius, out);
}

// Round 10
// 112.546 us; speedup vs baseline: 1.0541x; 1.0010x over previous
//
#include <hip/hip_runtime.h>

// PointSIFT: octant-wise nearest neighbor within radius + group.
// B=2, N=4096, C=64 fixed; xyz uniform in [0,1)^3, radius=0.25.
//
// Two-kernel design:
//   1. build_grid: counting-sort points into a 4x4x4 cell grid (cell width
//      0.25 = radius). Sorted float4 = (x,y,z, orig_idx bits) in d_ws.
//   2. select_gather: block = 8 consecutive SORTED queries (spatially tight).
//      Candidate box = cells overlapping [qmin-r, qmax+r] per axis (superset
//      of all valid candidates). Scoreboard = packed u64 (key<<32|idx) kept
//      in REGISTERS (no DS ops in the hot loop — R9's LDS ds_min_u64 atomic
//      was the suspected serializer). Winner = lexicographic u64 min, which
//      reproduces the reference's first-min + original-index tie-break
//      exactly and is scan-order-independent. Gather fused in the epilogue.
//
// Packed key: hi = float_bits(dist) - (float_bits(1e-10f)+1)
//   - dist <= 1e-10 (incl. self) wraps to huge            -> loses
//   - dist >= judge forced to 0xFFFFFFFF (strict-< exact) -> loses
//   - valid dists monotone; ties on key fall to min orig idx = ref tie-break
#define BB 2
#define NN 4096
#define CC 64
#define QPB 8               // queries per select block (sorted order)
#define TPQ 32              // threads per query
#define NT 256              // threads per select block

// flat output layout (all float32):
//   out0 grouped_xyz   [B,N,8,3]
//   out1 grouped_points[B,N,8,67]
//   out2 idx (as float)[B,N,8]
#define OUT0_OFF 0
#define OUT1_OFF (BB * NN * 8 * 3)               /* 196608 */
#define OUT2_OFF (OUT1_OFF + BB * NN * 8 * 67)   /* 4587520 */

// d_ws layout: sorted float4 [B*NN], then offsets int [B*65]
#define WS_SORTED_BYTES (BB * NN * 16)

__global__ __launch_bounds__(1024) void build_grid(
    const float* __restrict__ xyz, float4* __restrict__ sorted,
    int* __restrict__ offsets)
{
    __shared__ int hist[64];
    __shared__ int offs[65];
    const int b = blockIdx.x;
    const int tid = threadIdx.x;
    if (tid < 64) hist[tid] = 0;
    __syncthreads();
    const float* src = xyz + (size_t)b * NN * 3;
    #pragma unroll
    for (int p = tid; p < NN; p += 1024) {
        float x = src[p * 3 + 0], y = src[p * 3 + 1], z = src[p * 3 + 2];
        int cell = (((int)(x * 4.0f)) << 4) | (((int)(y * 4.0f)) << 2)
                 | ((int)(z * 4.0f));            // x in [0,1) -> cell in [0,64)
        atomicAdd(&hist[cell], 1);
    }
    __syncthreads();
    if (tid < 64) {                              // wave 0: shfl prefix scan
        int inc = hist[tid];
        #pragma unroll
        for (int d = 1; d < 64; d <<= 1) {
            int u = __shfl_up(inc, d, 64);
            if (tid >= d) inc += u;
        }
        offs[tid + 1] = inc;                     // inclusive -> offs[1..64]
        if (tid == 0) offs[0] = 0;
    }
    __syncthreads();
    if (tid < 65) offsets[b * 65 + tid] = offs[tid];
    if (tid < 64) hist[tid] = offs[tid];         // reuse as scatter cursors
    __syncthreads();
    float4* dst = sorted + (size_t)b * NN;
    #pragma unroll
    for (int p = tid; p < NN; p += 1024) {
        float x = src[p * 3 + 0], y = src[p * 3 + 1], z = src[p * 3 + 2];
        int cell = (((int)(x * 4.0f)) << 4) | (((int)(y * 4.0f)) << 2)
                 | ((int)(z * 4.0f));
        int pos = atomicAdd(&hist[cell], 1);     // order within cell arbitrary
        dst[pos] = make_float4(x, y, z, __uint_as_float((unsigned)p));
    }
}

__global__ __launch_bounds__(NT, 4) void select_gather(
    const float4* __restrict__ sorted, const int* __restrict__ offsets,
    const float* __restrict__ xyz, const float* __restrict__ points,
    const float* __restrict__ radius_p, float* __restrict__ out)
{
    __shared__ int s_off[65];
    __shared__ int s_res[QPB * 8];               // winners per (query,octant)

    const int tid = threadIdx.x;
    const int blk = blockIdx.x;
    const int b = blk >> 9;                      // 512 blocks per batch
    const int qslot = (blk & 511) * QPB;         // sorted-array slot base
    const float4* sb = sorted + (size_t)b * NN;

    if (tid < 65) s_off[tid] = offsets[b * 65 + tid];

    const float r = radius_p[0];
    const float judge = __fmul_rn(r, r);
    const unsigned OFFC = __float_as_uint(1e-10f) + 1u;
    const unsigned seedkey = __float_as_uint(judge) - OFFC;

    // own query (from sorted array; coords are bit-identical copies)
    const int g = tid >> 5;                      // query group 0..7
    const float4 q = sb[qslot + g];
    const unsigned n = __float_as_uint(q.w);     // original index
    const float qx = q.x, qy = q.y, qz = q.z;
    const int sub = tid & (TPQ - 1);

    // register scoreboard, packed (key<<32 | orig_idx), seeded w/ diagonal
    unsigned long long bv[8];
    const unsigned long long seed64 = ((unsigned long long)seedkey << 32) | n;
    #pragma unroll
    for (int o = 0; o < 8; ++o) bv[o] = seed64;

    // block candidate box: cells overlapping [min-r, max+r] over the block's
    // 8 queries (uniform across threads -> no divergence)
    float mnx = 1e9f, mxx = -1e9f, mny = 1e9f, mxy = -1e9f, mnz = 1e9f, mxz = -1e9f;
    #pragma unroll
    for (int k = 0; k < QPB; ++k) {
        float4 qq = sb[qslot + k];
        mnx = fminf(mnx, qq.x); mxx = fmaxf(mxx, qq.x);
        mny = fminf(mny, qq.y); mxy = fmaxf(mxy, qq.y);
        mnz = fminf(mnz, qq.z); mxz = fmaxf(mxz, qq.z);
    }
    const int lx = max(0, (int)((mnx - r) * 4.0f));
    const int hx = min(3, (int)((mxx + r) * 4.0f));
    const int ly = max(0, (int)((mny - r) * 4.0f));
    const int hy = min(3, (int)((mxy + r) * 4.0f));
    const int lz = max(0, (int)((mnz - r) * 4.0f));
    const int hz = min(3, (int)((mxz + r) * 4.0f));

    __syncthreads();                             // s_off ready

    for (int cx = lx; cx <= hx; ++cx) {
        for (int cy = ly; cy <= hy; ++cy) {
            const int cb = (cx << 4) | (cy << 2);
            const int s = s_off[cb + lz];
            const int e = s_off[cb + hz + 1];    // cz-contiguous run
            #pragma unroll 2
            for (int p = s + sub; p < e; p += TPQ) {
                float4 c = sb[p];
                // diff = candidate - query, fp32, no contraction (match ref)
                float dx = __fsub_rn(c.x, qx);
                float dy = __fsub_rn(c.y, qy);
                float dz = __fsub_rn(c.z, qz);
                float dist = __fadd_rn(__fadd_rn(__fmul_rn(dx, dx),
                                                 __fmul_rn(dy, dy)),
                                       __fmul_rn(dz, dz));
                unsigned ikey = __float_as_uint(dist) - OFFC;
                ikey = (dist >= judge) ? 0xFFFFFFFFu : ikey;
                // octant code = trunc(d+1.0f) dot [4,2,1]; coords in [0,1)
                // -> d+1.0f in (0,2) -> each bit already 0/1
                int code = (((int)__fadd_rn(dx, 1.0f)) * 4 +
                            ((int)__fadd_rn(dy, 1.0f)) * 2 +
                            ((int)__fadd_rn(dz, 1.0f)));
                unsigned long long key64 =
                    ((unsigned long long)ikey << 32) |
                    (unsigned long long)__float_as_uint(c.w);
                // register update: 6 VALU per octant, no DS ops
                #pragma unroll
                for (int o = 0; o < 8; ++o) {
                    unsigned long long cand =
                        (code == o) ? key64 : 0xFFFFFFFFFFFFFFFFull;
                    bv[o] = (cand < bv[o]) ? cand : bv[o];
                }
            }
        }
    }

    // butterfly reduce over the 32 stripe-threads of this query (lanes are
    // 32-aligned within the wave); packed u64 min = first-min + idx tie-break
    #pragma unroll
    for (int mm = 1; mm < TPQ; mm <<= 1) {
        #pragma unroll
        for (int o = 0; o < 8; ++o) {
            unsigned long long ov = __shfl_xor(bv[o], mm, 64);
            if (ov < bv[o]) bv[o] = ov;
        }
    }

    // stripe-leader publishes winners + writes out2
    if (sub == 0) {
        const size_t tb = ((size_t)b * NN + n) * 8;
        #pragma unroll
        for (int o = 0; o < 8; ++o) {
            int w = (int)(unsigned)(bv[o] & 0xFFFFFFFFu);
            s_res[g * 8 + o] = w;
            out[OUT2_OFF + tb + o] = (float)w;
        }
    }
    __syncthreads();

    // fused gather: each query-group (32 lanes) writes its own 8 tuples.
    // out1 row = 67 floats: c<3 -> grouped_xyz, else points[b,i,c-3].
    const float* xb = xyz + (size_t)b * NN * 3;
    const float* pb = points + (size_t)b * NN * CC;
    #pragma unroll
    for (int o = 0; o < 8; ++o) {
        const int i = s_res[g * 8 + o];
        const size_t t = ((size_t)b * NN + n) * 8 + o;
        // c = sub (0..31): 3 xyz + feats 0..28
        {
            const int c = sub;
            float v;
            if (c < 3) {
                v = __fsub_rn(xb[i * 3 + c], xb[n * 3 + c]);
                out[OUT0_OFF + t * 3 + c] = v;
            } else {
                v = pb[(size_t)i * CC + (c - 3)];
            }
            out[OUT1_OFF + t * 67 + c] = v;
        }
        // c = sub+32 (32..63): feats 29..60
        {
            const int c = sub + 32;
            out[OUT1_OFF + t * 67 + c] = pb[(size_t)i * CC + (c - 3)];
        }
        // c = sub+64 (64..66): feats 61..63
        if (sub < 3) {
            const int c = sub + 64;
            out[OUT1_OFF + t * 67 + c] = pb[(size_t)i * CC + (c - 3)];
        }
    }
}

extern "C" void kernel_launch(void* const* d_in, const int* in_sizes, int n_in,
                              void* d_out, int out_size, void* d_ws, size_t ws_size,
                              hipStream_t stream) {
    const float* xyz    = (const float*)d_in[0];
    const float* points = (const float*)d_in[1];
    const float* radius = (const float*)d_in[2];
    float* out = (float*)d_out;
    float4* ws_sorted = (float4*)d_ws;
    int* ws_offsets = (int*)((char*)d_ws + WS_SORTED_BYTES);

    // 1: counting-sort into 4x4x4 cells (one block per batch)
    hipLaunchKernelGGL(build_grid, dim3(BB), dim3(1024), 0, stream,
                       xyz, ws_sorted, ws_offsets);
    // 2: pruned octant select + fused gather (1024 blocks)
    hipLaunchKernelGGL(select_gather,
                       dim3(BB * (NN / QPB)), dim3(NT), 0, stream,
                       ws_sorted, ws_offsets, xyz, points, radius, out);
}

// Round 11
// 103.163 us; speedup vs baseline: 1.1499x; 1.0910x over previous
//
#include <hip/hip_runtime.h>

// PointSIFT: octant-wise nearest neighbor within radius + group.
// B=2, N=4096, C=64 fixed; xyz uniform in [0,1)^3, radius=0.25.
//
// Three-kernel design (split for rocprof attribution):
//   1. build_grid: counting-sort points into a 4x4x4 cell grid (cell width
//      0.25 = radius). Sorted float4 = (x,y,z, orig_idx bits) in d_ws.
//   2. select: ONE WAVE PER QUERY (TPQ=64, QPB=4). Per-query candidate box
//      [q-r, q+r] -> always <= 27 cells (no straggler blowup). Register
//      scoreboard of packed u64 (key<<32|idx); lexicographic u64 min
//      reproduces the reference's first-min + original-index tie-break
//      exactly and is scan-order-independent. Writes out2 (idx) directly.
//   3. gather: wave-per-tuple, 8 tuples in flight per wave, reads out2.
//
// Packed key: hi = float_bits(dist) - (float_bits(1e-10f)+1)
//   - dist <= 1e-10 (incl. self) wraps to huge            -> loses
//   - dist >= judge forced to 0xFFFFFFFF (strict-< exact) -> loses
//   - valid dists monotone; ties on key fall to min orig idx = ref tie-break
#define BB 2
#define NN 4096
#define CC 64
#define QPB 4               // queries per select block (one per wave)
#define TPQ 64              // threads per query = full wave
#define NT 256              // threads per select block

// flat output layout (all float32):
//   out0 grouped_xyz   [B,N,8,3]
//   out1 grouped_points[B,N,8,67]
//   out2 idx (as float)[B,N,8]
#define OUT0_OFF 0
#define OUT1_OFF (BB * NN * 8 * 3)               /* 196608 */
#define OUT2_OFF (OUT1_OFF + BB * NN * 8 * 67)   /* 4587520 */

// d_ws layout: sorted float4 [B*NN], then offsets int [B*65]
#define WS_SORTED_BYTES (BB * NN * 16)

__global__ __launch_bounds__(1024) void build_grid(
    const float* __restrict__ xyz, float4* __restrict__ sorted,
    int* __restrict__ offsets)
{
    __shared__ int hist[64];
    __shared__ int offs[65];
    const int b = blockIdx.x;
    const int tid = threadIdx.x;
    if (tid < 64) hist[tid] = 0;
    __syncthreads();
    const float* src = xyz + (size_t)b * NN * 3;
    #pragma unroll
    for (int p = tid; p < NN; p += 1024) {
        float x = src[p * 3 + 0], y = src[p * 3 + 1], z = src[p * 3 + 2];
        int cell = (((int)(x * 4.0f)) << 4) | (((int)(y * 4.0f)) << 2)
                 | ((int)(z * 4.0f));            // x in [0,1) -> cell in [0,64)
        atomicAdd(&hist[cell], 1);
    }
    __syncthreads();
    if (tid < 64) {                              // wave 0: shfl prefix scan
        int inc = hist[tid];
        #pragma unroll
        for (int d = 1; d < 64; d <<= 1) {
            int u = __shfl_up(inc, d, 64);
            if (tid >= d) inc += u;
        }
        offs[tid + 1] = inc;                     // inclusive -> offs[1..64]
        if (tid == 0) offs[0] = 0;
    }
    __syncthreads();
    if (tid < 65) offsets[b * 65 + tid] = offs[tid];
    if (tid < 64) hist[tid] = offs[tid];         // reuse as scatter cursors
    __syncthreads();
    float4* dst = sorted + (size_t)b * NN;
    #pragma unroll
    for (int p = tid; p < NN; p += 1024) {
        float x = src[p * 3 + 0], y = src[p * 3 + 1], z = src[p * 3 + 2];
        int cell = (((int)(x * 4.0f)) << 4) | (((int)(y * 4.0f)) << 2)
                 | ((int)(z * 4.0f));
        int pos = atomicAdd(&hist[cell], 1);     // order within cell arbitrary
        dst[pos] = make_float4(x, y, z, __uint_as_float((unsigned)p));
    }
}

__global__ __launch_bounds__(NT, 8) void pointsift_select(
    const float4* __restrict__ sorted, const int* __restrict__ offsets,
    const float* __restrict__ radius_p, float* __restrict__ out)
{
    __shared__ int s_off[65];

    const int tid = threadIdx.x;
    const int blk = blockIdx.x;
    const int b = blk >> 10;                     // 1024 blocks per batch
    const int qslot = (blk & 1023) * QPB;        // sorted-array slot base
    const float4* sb = sorted + (size_t)b * NN;

    if (tid < 65) s_off[tid] = offsets[b * 65 + tid];

    const float r = radius_p[0];
    const float judge = __fmul_rn(r, r);
    const unsigned OFFC = __float_as_uint(1e-10f) + 1u;
    const unsigned seedkey = __float_as_uint(judge) - OFFC;

    // own query: one WAVE per query (box is wave-uniform -> no divergence)
    const int g = tid >> 6;                      // query group = wave id 0..3
    const float4 q = sb[qslot + g];
    const unsigned n = __float_as_uint(q.w);     // original index
    const float qx = q.x, qy = q.y, qz = q.z;
    const int sub = tid & 63;

    // register scoreboard, packed (key<<32 | orig_idx), seeded w/ diagonal
    unsigned long long bv[8];
    const unsigned long long seed64 = ((unsigned long long)seedkey << 32) | n;
    #pragma unroll
    for (int o = 0; o < 8; ++o) bv[o] = seed64;

    // per-query candidate box: cells overlapping [q-r, q+r] (<= 3 per axis)
    const int lx = max(0, (int)((qx - r) * 4.0f));
    const int hx = min(3, (int)((qx + r) * 4.0f));
    const int ly = max(0, (int)((qy - r) * 4.0f));
    const int hy = min(3, (int)((qy + r) * 4.0f));
    const int lz = max(0, (int)((qz - r) * 4.0f));
    const int hz = min(3, (int)((qz + r) * 4.0f));

    __syncthreads();                             // s_off ready

    for (int cx = lx; cx <= hx; ++cx) {
        for (int cy = ly; cy <= hy; ++cy) {
            const int cb = (cx << 4) | (cy << 2);
            const int s = s_off[cb + lz];
            const int e = s_off[cb + hz + 1];    // cz-contiguous run
            #pragma unroll 2
            for (int p = s + sub; p < e; p += TPQ) {
                float4 c = sb[p];
                // diff = candidate - query, fp32, no contraction (match ref)
                float dx = __fsub_rn(c.x, qx);
                float dy = __fsub_rn(c.y, qy);
                float dz = __fsub_rn(c.z, qz);
                float dist = __fadd_rn(__fadd_rn(__fmul_rn(dx, dx),
                                                 __fmul_rn(dy, dy)),
                                       __fmul_rn(dz, dz));
                unsigned ikey = __float_as_uint(dist) - OFFC;
                ikey = (dist >= judge) ? 0xFFFFFFFFu : ikey;
                // octant code = trunc(d+1.0f) dot [4,2,1]; coords in [0,1)
                // -> d+1.0f in (0,2) -> each bit already 0/1
                int code = (((int)__fadd_rn(dx, 1.0f)) * 4 +
                            ((int)__fadd_rn(dy, 1.0f)) * 2 +
                            ((int)__fadd_rn(dz, 1.0f)));
                unsigned long long key64 =
                    ((unsigned long long)ikey << 32) |
                    (unsigned long long)__float_as_uint(c.w);
                // register update: ~6 VALU per octant, no DS ops
                #pragma unroll
                for (int o = 0; o < 8; ++o) {
                    unsigned long long cand =
                        (code == o) ? key64 : 0xFFFFFFFFFFFFFFFFull;
                    bv[o] = (cand < bv[o]) ? cand : bv[o];
                }
            }
        }
    }

    // butterfly reduce across the full 64-lane wave
    #pragma unroll
    for (int mm = 1; mm < TPQ; mm <<= 1) {
        #pragma unroll
        for (int o = 0; o < 8; ++o) {
            unsigned long long ov = __shfl_xor(bv[o], mm, 64);
            if (ov < bv[o]) bv[o] = ov;
        }
    }

    // lane 0 of each wave writes its query's 8 winners to out2
    if (sub == 0) {
        const size_t tb = ((size_t)b * NN + n) * 8;
        #pragma unroll
        for (int o = 0; o < 8; ++o)
            out[OUT2_OFF + tb + o] = (float)(unsigned)(bv[o] & 0xFFFFFFFFu);
    }
}

// gather: wave per tuple batch-of-8. Lane c (0..63):
//   ch c of out1 row t: c<3 -> grouped_xyz (also -> out0), else feat c-3
//   lanes 61..63 additionally write ch 64..66 (feats 61..63)
#define GT_TPW 8            // tuples per wave
__global__ __launch_bounds__(256, 8) void pointsift_gather(
    const float* __restrict__ xyz, const float* __restrict__ points,
    float* __restrict__ out)
{
    const int tid = threadIdx.x;
    const int wave = tid >> 6;
    const int lane = tid & 63;
    const int base_t = (blockIdx.x * 4 + wave) * GT_TPW;

    // prefetch the 8 winner indices (independent broadcast loads)
    int idxs[GT_TPW];
    #pragma unroll
    for (int k = 0; k < GT_TPW; ++k)
        idxs[k] = (int)out[OUT2_OFF + base_t + k];

    #pragma unroll
    for (int k = 0; k < GT_TPW; ++k) {
        const int t = base_t + k;
        const int i = idxs[k];
        const int bn = t >> 3;                   // b*N + n
        const int b = bn >> 12;
        const int n = bn & (NN - 1);
        const float* xb = xyz + (size_t)b * NN * 3;
        const float* pb = points + (size_t)b * NN * CC;
        float v;
        if (lane < 3) v = __fsub_rn(xb[i * 3 + lane], xb[n * 3 + lane]);
        else          v = pb[(size_t)i * CC + (lane - 3)];
        out[OUT1_OFF + (size_t)t * 67 + lane] = v;           // ch 0..63
        if (lane >= 61)                                      // ch 64..66
            out[OUT1_OFF + (size_t)t * 67 + (lane + 3)] = pb[(size_t)i * CC + lane];
        if (lane < 3)
            out[OUT0_OFF + (size_t)t * 3 + lane] = v;
    }
}

extern "C" void kernel_launch(void* const* d_in, const int* in_sizes, int n_in,
                              void* d_out, int out_size, void* d_ws, size_t ws_size,
                              hipStream_t stream) {
    const float* xyz    = (const float*)d_in[0];
    const float* points = (const float*)d_in[1];
    const float* radius = (const float*)d_in[2];
    float* out = (float*)d_out;
    float4* ws_sorted = (float4*)d_ws;
    int* ws_offsets = (int*)((char*)d_ws + WS_SORTED_BYTES);

    // 1: counting-sort into 4x4x4 cells (one block per batch)
    hipLaunchKernelGGL(build_grid, dim3(BB), dim3(1024), 0, stream,
                       xyz, ws_sorted, ws_offsets);
    // 2: per-query-wave pruned octant select -> out2 (2048 blocks)
    hipLaunchKernelGGL(pointsift_select,
                       dim3(BB * (NN / QPB)), dim3(NT), 0, stream,
                       ws_sorted, ws_offsets, radius, out);
    // 3: gather, wave per 8 tuples (131072 tuples -> 4096 blocks)
    hipLaunchKernelGGL(pointsift_gather,
                       dim3(BB * NN * 8 / (4 * GT_TPW)), dim3(256), 0, stream,
                       xyz, points, out);
}

// Round 12
// 102.555 us; speedup vs baseline: 1.1567x; 1.0059x over previous
//
#include <hip/hip_runtime.h>

// PointSIFT: octant-wise nearest neighbor within radius + group.
// B=2, N=4096, C=64 fixed; xyz uniform in [0,1)^3, radius=0.25.
//
// Two-kernel design:
//   1. build_grid: counting-sort points into a 4x4x4 cell grid (cell width
//      0.25 = radius). Sorted float4 = (x,y,z, orig_idx bits) in d_ws.
//   2. select_gather: ONE WAVE PER QUERY. Per-query candidate box [q-r,q+r]
//      (<=27 cells, no straggler blowup). Register scoreboard of packed u64
//      (key<<32|idx); lexicographic u64 min == reference first-min +
//      original-index tie-break, scan-order-independent. After the 64-lane
//      butterfly EVERY lane holds all 8 winners -> gather fused in the
//      epilogue with zero LDS / zero extra loads for indices.
//
// Packed key: hi = float_bits(dist) - (float_bits(1e-10f)+1)
//   - dist <= 1e-10 (incl. self) wraps to huge            -> loses
//   - dist >= judge forced to 0xFFFFFFFF (strict-< exact) -> loses
//   - valid dists monotone; ties on key fall to min orig idx = ref tie-break
#define BB 2
#define NN 4096
#define CC 64
#define QPB 4               // queries per select block (one per wave)
#define TPQ 64              // threads per query = full wave
#define NT 256              // threads per select block

// flat output layout (all float32):
//   out0 grouped_xyz   [B,N,8,3]
//   out1 grouped_points[B,N,8,67]
//   out2 idx (as float)[B,N,8]
#define OUT0_OFF 0
#define OUT1_OFF (BB * NN * 8 * 3)               /* 196608 */
#define OUT2_OFF (OUT1_OFF + BB * NN * 8 * 67)   /* 4587520 */

// d_ws layout: sorted float4 [B*NN], then offsets int [B*65]
#define WS_SORTED_BYTES (BB * NN * 16)

__global__ __launch_bounds__(1024) void build_grid(
    const float* __restrict__ xyz, float4* __restrict__ sorted,
    int* __restrict__ offsets)
{
    __shared__ int hist[64];
    __shared__ int offs[65];
    const int b = blockIdx.x;
    const int tid = threadIdx.x;
    if (tid < 64) hist[tid] = 0;
    __syncthreads();
    const float* src = xyz + (size_t)b * NN * 3;
    #pragma unroll
    for (int p = tid; p < NN; p += 1024) {
        float x = src[p * 3 + 0], y = src[p * 3 + 1], z = src[p * 3 + 2];
        int cell = (((int)(x * 4.0f)) << 4) | (((int)(y * 4.0f)) << 2)
                 | ((int)(z * 4.0f));            // x in [0,1) -> cell in [0,64)
        atomicAdd(&hist[cell], 1);
    }
    __syncthreads();
    if (tid < 64) {                              // wave 0: shfl prefix scan
        int inc = hist[tid];
        #pragma unroll
        for (int d = 1; d < 64; d <<= 1) {
            int u = __shfl_up(inc, d, 64);
            if (tid >= d) inc += u;
        }
        offs[tid + 1] = inc;                     // inclusive -> offs[1..64]
        if (tid == 0) offs[0] = 0;
    }
    __syncthreads();
    if (tid < 65) offsets[b * 65 + tid] = offs[tid];
    if (tid < 64) hist[tid] = offs[tid];         // reuse as scatter cursors
    __syncthreads();
    float4* dst = sorted + (size_t)b * NN;
    #pragma unroll
    for (int p = tid; p < NN; p += 1024) {
        float x = src[p * 3 + 0], y = src[p * 3 + 1], z = src[p * 3 + 2];
        int cell = (((int)(x * 4.0f)) << 4) | (((int)(y * 4.0f)) << 2)
                 | ((int)(z * 4.0f));
        int pos = atomicAdd(&hist[cell], 1);     // order within cell arbitrary
        dst[pos] = make_float4(x, y, z, __uint_as_float((unsigned)p));
    }
}

__global__ __launch_bounds__(NT, 8) void select_gather(
    const float4* __restrict__ sorted, const int* __restrict__ offsets,
    const float* __restrict__ xyz, const float* __restrict__ points,
    const float* __restrict__ radius_p, float* __restrict__ out)
{
    __shared__ int s_off[65];

    const int tid = threadIdx.x;
    const int blk = blockIdx.x;
    const int b = blk >> 10;                     // 1024 blocks per batch
    const int qslot = (blk & 1023) * QPB;        // sorted-array slot base
    const float4* sb = sorted + (size_t)b * NN;

    if (tid < 65) s_off[tid] = offsets[b * 65 + tid];

    const float r = radius_p[0];
    const float judge = __fmul_rn(r, r);
    const unsigned OFFC = __float_as_uint(1e-10f) + 1u;
    const unsigned seedkey = __float_as_uint(judge) - OFFC;

    // own query: one WAVE per query (box is wave-uniform -> no divergence)
    const int g = tid >> 6;                      // query group = wave id 0..3
    const float4 q = sb[qslot + g];
    const unsigned n = __float_as_uint(q.w);     // original index
    const float qx = q.x, qy = q.y, qz = q.z;
    const int sub = tid & 63;

    // register scoreboard, packed (key<<32 | orig_idx), seeded w/ diagonal
    unsigned long long bv[8];
    const unsigned long long seed64 = ((unsigned long long)seedkey << 32) | n;
    #pragma unroll
    for (int o = 0; o < 8; ++o) bv[o] = seed64;

    // per-query candidate box: cells overlapping [q-r, q+r] (<= 3 per axis)
    const int lx = max(0, (int)((qx - r) * 4.0f));
    const int hx = min(3, (int)((qx + r) * 4.0f));
    const int ly = max(0, (int)((qy - r) * 4.0f));
    const int hy = min(3, (int)((qy + r) * 4.0f));
    const int lz = max(0, (int)((qz - r) * 4.0f));
    const int hz = min(3, (int)((qz + r) * 4.0f));

    __syncthreads();                             // s_off ready

    for (int cx = lx; cx <= hx; ++cx) {
        for (int cy = ly; cy <= hy; ++cy) {
            const int cb = (cx << 4) | (cy << 2);
            const int s = s_off[cb + lz];
            const int e = s_off[cb + hz + 1];    // cz-contiguous run
            #pragma unroll 2
            for (int p = s + sub; p < e; p += TPQ) {
                float4 c = sb[p];
                // diff = candidate - query, fp32, no contraction (match ref)
                float dx = __fsub_rn(c.x, qx);
                float dy = __fsub_rn(c.y, qy);
                float dz = __fsub_rn(c.z, qz);
                float dist = __fadd_rn(__fadd_rn(__fmul_rn(dx, dx),
                                                 __fmul_rn(dy, dy)),
                                       __fmul_rn(dz, dz));
                unsigned ikey = __float_as_uint(dist) - OFFC;
                ikey = (dist >= judge) ? 0xFFFFFFFFu : ikey;
                // octant code = trunc(d+1.0f) dot [4,2,1]; coords in [0,1)
                // -> d+1.0f in (0,2) -> each bit already 0/1
                int code = (((int)__fadd_rn(dx, 1.0f)) * 4 +
                            ((int)__fadd_rn(dy, 1.0f)) * 2 +
                            ((int)__fadd_rn(dz, 1.0f)));
                unsigned long long key64 =
                    ((unsigned long long)ikey << 32) |
                    (unsigned long long)__float_as_uint(c.w);
                // register update: ~6 VALU per octant, no DS ops
                #pragma unroll
                for (int o = 0; o < 8; ++o) {
                    unsigned long long cand =
                        (code == o) ? key64 : 0xFFFFFFFFFFFFFFFFull;
                    bv[o] = (cand < bv[o]) ? cand : bv[o];
                }
            }
        }
    }

    // butterfly reduce across the full 64-lane wave; afterwards EVERY lane
    // holds the winning (key, idx) for all 8 octants
    #pragma unroll
    for (int mm = 1; mm < TPQ; mm <<= 1) {
        #pragma unroll
        for (int o = 0; o < 8; ++o) {
            unsigned long long ov = __shfl_xor(bv[o], mm, 64);
            if (ov < bv[o]) bv[o] = ov;
        }
    }

    // ---- fused epilogue: this wave writes its query's entire output ----
    const size_t tb = ((size_t)b * NN + n) * 8;
    // out2: lanes 0..7 each store one octant's idx (single store instr)
    if (sub < 8)
        out[OUT2_OFF + tb + sub] = (float)(unsigned)(bv[sub] & 0xFFFFFFFFu);

    const float* xb = xyz + (size_t)b * NN * 3;
    const float* pb = points + (size_t)b * NN * CC;
    // per-lane query component for the xyz-diff lanes (0..2)
    const float qc = (sub == 0) ? qx : ((sub == 1) ? qy : qz);
    #pragma unroll
    for (int o = 0; o < 8; ++o) {
        const int i = (int)(unsigned)(bv[o] & 0xFFFFFFFFu);  // wave-uniform
        const size_t t = tb + o;
        float v;
        if (sub < 3) v = __fsub_rn(xb[i * 3 + sub], qc);
        else         v = pb[(size_t)i * CC + (sub - 3)];
        __builtin_nontemporal_store(v, &out[OUT1_OFF + t * 67 + sub]);
        if (sub >= 61)                                       // ch 64..66
            __builtin_nontemporal_store(pb[(size_t)i * CC + sub],
                                        &out[OUT1_OFF + t * 67 + (sub + 3)]);
        if (sub < 3)
            __builtin_nontemporal_store(v, &out[OUT0_OFF + t * 3 + sub]);
    }
}

extern "C" void kernel_launch(void* const* d_in, const int* in_sizes, int n_in,
                              void* d_out, int out_size, void* d_ws, size_t ws_size,
                              hipStream_t stream) {
    const float* xyz    = (const float*)d_in[0];
    const float* points = (const float*)d_in[1];
    const float* radius = (const float*)d_in[2];
    float* out = (float*)d_out;
    float4* ws_sorted = (float4*)d_ws;
    int* ws_offsets = (int*)((char*)d_ws + WS_SORTED_BYTES);

    // 1: counting-sort into 4x4x4 cells (one block per batch)
    hipLaunchKernelGGL(build_grid, dim3(BB), dim3(1024), 0, stream,
                       xyz, ws_sorted, ws_offsets);
    // 2: per-query-wave pruned octant select + fused gather (2048 blocks)
    hipLaunchKernelGGL(select_gather,
                       dim3(BB * (NN / QPB)), dim3(NT), 0, stream,
                       ws_sorted, ws_offsets, xyz, points, radius, out);
}

// Round 13
// 91.675 us; speedup vs baseline: 1.2940x; 1.1187x over previous
//
#include <hip/hip_runtime.h>

// PointSIFT: octant-wise nearest neighbor within radius + group.
// B=2, N=4096, C=64 fixed; xyz uniform in [0,1)^3, radius=0.25.
//
// Two-kernel design:
//   1. build_grid: counting-sort points into a 4x4x4 cell grid (cell width
//      0.25 = radius). Sorted float4 = (x,y,z, orig_idx bits) in d_ws.
//   2. select_gather: ONE WAVE PER QUERY, per-query candidate box [q-r,q+r].
//      Scoreboard = 8 u64 slots PER WAVE in LDS, updated with a predicated
//      fire-and-forget ds_min_u64 (only lanes with dist < judge issue it —
//      ~15% duty). Lexicographic u64 min of (key<<32|idx) == reference
//      first-min + original-index tie-break, scan-order-independent. Winners
//      are read straight from the wave's LDS slots (same-wave DS ordering is
//      in-order); gather fused in the epilogue.
//
// Packed key: hi = float_bits(dist) - (float_bits(1e-10f)+1)
//   - dist <= 1e-10 (incl. self) wraps to huge -> loses to the seed
//   - dist >= judge never issues the atomic (strict-< exact)
//   - valid dists monotone; ties on key fall to min orig idx = ref tie-break
#define BB 2
#define NN 4096
#define CC 64
#define QPB 4               // queries per select block (one per wave)
#define TPQ 64              // threads per query = full wave
#define NT 256              // threads per select block

// flat output layout (all float32):
//   out0 grouped_xyz   [B,N,8,3]
//   out1 grouped_points[B,N,8,67]
//   out2 idx (as float)[B,N,8]
#define OUT0_OFF 0
#define OUT1_OFF (BB * NN * 8 * 3)               /* 196608 */
#define OUT2_OFF (OUT1_OFF + BB * NN * 8 * 67)   /* 4587520 */

// d_ws layout: sorted float4 [B*NN], then offsets int [B*65]
#define WS_SORTED_BYTES (BB * NN * 16)

__global__ __launch_bounds__(1024) void build_grid(
    const float* __restrict__ xyz, float4* __restrict__ sorted,
    int* __restrict__ offsets)
{
    __shared__ int hist[64];
    __shared__ int offs[65];
    const int b = blockIdx.x;
    const int tid = threadIdx.x;
    if (tid < 64) hist[tid] = 0;
    __syncthreads();
    const float* src = xyz + (size_t)b * NN * 3;
    #pragma unroll
    for (int p = tid; p < NN; p += 1024) {
        float x = src[p * 3 + 0], y = src[p * 3 + 1], z = src[p * 3 + 2];
        int cell = (((int)(x * 4.0f)) << 4) | (((int)(y * 4.0f)) << 2)
                 | ((int)(z * 4.0f));            // x in [0,1) -> cell in [0,64)
        atomicAdd(&hist[cell], 1);
    }
    __syncthreads();
    if (tid < 64) {                              // wave 0: shfl prefix scan
        int inc = hist[tid];
        #pragma unroll
        for (int d = 1; d < 64; d <<= 1) {
            int u = __shfl_up(inc, d, 64);
            if (tid >= d) inc += u;
        }
        offs[tid + 1] = inc;                     // inclusive -> offs[1..64]
        if (tid == 0) offs[0] = 0;
    }
    __syncthreads();
    if (tid < 65) offsets[b * 65 + tid] = offs[tid];
    if (tid < 64) hist[tid] = offs[tid];         // reuse as scatter cursors
    __syncthreads();
    float4* dst = sorted + (size_t)b * NN;
    #pragma unroll
    for (int p = tid; p < NN; p += 1024) {
        float x = src[p * 3 + 0], y = src[p * 3 + 1], z = src[p * 3 + 2];
        int cell = (((int)(x * 4.0f)) << 4) | (((int)(y * 4.0f)) << 2)
                 | ((int)(z * 4.0f));
        int pos = atomicAdd(&hist[cell], 1);     // order within cell arbitrary
        dst[pos] = make_float4(x, y, z, __uint_as_float((unsigned)p));
    }
}

__global__ __launch_bounds__(NT, 8) void select_gather(
    const float4* __restrict__ sorted, const int* __restrict__ offsets,
    const float* __restrict__ xyz, const float* __restrict__ points,
    const float* __restrict__ radius_p, float* __restrict__ out)
{
    __shared__ int s_off[65];
    __shared__ unsigned long long s_sb[QPB * 8];  // 8 u64 slots per wave

    const int tid = threadIdx.x;
    const int blk = blockIdx.x;
    const int b = blk >> 10;                     // 1024 blocks per batch
    const int qslot = (blk & 1023) * QPB;        // sorted-array slot base
    const float4* sb = sorted + (size_t)b * NN;

    if (tid < 65) s_off[tid] = offsets[b * 65 + tid];

    const float r = radius_p[0];
    const float judge = __fmul_rn(r, r);
    const unsigned OFFC = __float_as_uint(1e-10f) + 1u;   // wrap offset
    const unsigned seedkey = __float_as_uint(judge) - OFFC;

    // own query: one WAVE per query (box is wave-uniform -> no divergence)
    const int g = tid >> 6;                      // query group = wave id 0..3
    const float4 q = sb[qslot + g];
    const unsigned n = __float_as_uint(q.w);     // original index
    const float qx = q.x, qy = q.y, qz = q.z;
    const int sub = tid & 63;

    // seed this wave's 8 slots (same-wave DS ops are in-order: seeds land
    // before any later atomic from this wave; no other wave touches them)
    const unsigned long long seed64 = ((unsigned long long)seedkey << 32) | n;
    if (sub < 8) s_sb[g * 8 + sub] = seed64;

    // per-query candidate box: cells overlapping [q-r, q+r] (<= 3 per axis)
    const int lx = max(0, (int)((qx - r) * 4.0f));
    const int hx = min(3, (int)((qx + r) * 4.0f));
    const int ly = max(0, (int)((qy - r) * 4.0f));
    const int hy = min(3, (int)((qy + r) * 4.0f));
    const int lz = max(0, (int)((qz - r) * 4.0f));
    const int hz = min(3, (int)((qz + r) * 4.0f));

    __syncthreads();                             // s_off ready

    for (int cx = lx; cx <= hx; ++cx) {
        for (int cy = ly; cy <= hy; ++cy) {
            const int cb = (cx << 4) | (cy << 2);
            const int s = s_off[cb + lz];
            const int e = s_off[cb + hz + 1];    // cz-contiguous run
            #pragma unroll 2
            for (int p = s + sub; p < e; p += TPQ) {
                float4 c = sb[p];
                // diff = candidate - query, fp32, no contraction (match ref)
                float dx = __fsub_rn(c.x, qx);
                float dy = __fsub_rn(c.y, qy);
                float dz = __fsub_rn(c.z, qz);
                float dist = __fadd_rn(__fadd_rn(__fmul_rn(dx, dx),
                                                 __fmul_rn(dy, dy)),
                                       __fmul_rn(dz, dz));
                // only ~15% of box candidates are inside the ball: everyone
                // else skips the scoreboard entirely (predicated atomic).
                if (dist < judge) {
                    // monotone packed key; dist<=1e-10 (incl. self) wraps to
                    // a huge key and loses to the seed automatically
                    unsigned ikey = __float_as_uint(dist) - OFFC;
                    // octant code = trunc(d+1.0f) dot [4,2,1]; coords in
                    // [0,1) -> d+1.0f in (0,2) -> each bit already 0/1
                    int code = (((int)__fadd_rn(dx, 1.0f)) * 4 +
                                ((int)__fadd_rn(dy, 1.0f)) * 2 +
                                ((int)__fadd_rn(dz, 1.0f)));
                    atomicMin(&s_sb[g * 8 + code],
                              ((unsigned long long)ikey << 32) |
                              (unsigned long long)__float_as_uint(c.w));
                }
            }
        }
    }

    // read winners straight from the wave's slots (in-order after atomics;
    // broadcast reads, no butterfly needed)
    unsigned idx8[8];
    #pragma unroll
    for (int o = 0; o < 8; ++o)
        idx8[o] = (unsigned)(s_sb[g * 8 + o] & 0xFFFFFFFFull);

    // ---- fused epilogue: this wave writes its query's entire output ----
    const size_t tb = ((size_t)b * NN + n) * 8;
    if (sub < 8)
        out[OUT2_OFF + tb + sub] = (float)idx8[sub];

    const float* xb = xyz + (size_t)b * NN * 3;
    const float* pb = points + (size_t)b * NN * CC;
    // per-lane query component for the xyz-diff lanes (0..2)
    const float qc = (sub == 0) ? qx : ((sub == 1) ? qy : qz);
    #pragma unroll
    for (int o = 0; o < 8; ++o) {
        const int i = (int)idx8[o];                          // wave-uniform
        const size_t t = tb + o;
        float v;
        if (sub < 3) v = __fsub_rn(xb[i * 3 + sub], qc);
        else         v = pb[(size_t)i * CC + (sub - 3)];
        __builtin_nontemporal_store(v, &out[OUT1_OFF + t * 67 + sub]);
        if (sub >= 61)                                       // ch 64..66
            __builtin_nontemporal_store(pb[(size_t)i * CC + sub],
                                        &out[OUT1_OFF + t * 67 + (sub + 3)]);
        if (sub < 3)
            __builtin_nontemporal_store(v, &out[OUT0_OFF + t * 3 + sub]);
    }
}

extern "C" void kernel_launch(void* const* d_in, const int* in_sizes, int n_in,
                              void* d_out, int out_size, void* d_ws, size_t ws_size,
                              hipStream_t stream) {
    const float* xyz    = (const float*)d_in[0];
    const float* points = (const float*)d_in[1];
    const float* radius = (const float*)d_in[2];
    float* out = (float*)d_out;
    float4* ws_sorted = (float4*)d_ws;
    int* ws_offsets = (int*)((char*)d_ws + WS_SORTED_BYTES);

    // 1: counting-sort into 4x4x4 cells (one block per batch)
    hipLaunchKernelGGL(build_grid, dim3(BB), dim3(1024), 0, stream,
                       xyz, ws_sorted, ws_offsets);
    // 2: per-query-wave pruned octant select + fused gather (2048 blocks)
    hipLaunchKernelGGL(select_gather,
                       dim3(BB * (NN / QPB)), dim3(NT), 0, stream,
                       ws_sorted, ws_offsets, xyz, points, radius, out);
}